// Round 1
// baseline (508.633 us; speedup 1.0000x reference)
//
#include <hip/hip_runtime.h>
#include <math.h>

// Problem geometry (compile-time constants from the reference)
#define BB 8
#define DD 472
#define CC 472
#define FH 56
#define FW 100
#define NPIX (FH * FW)          // 5600
#define NPIX_TOT (BB * NPIX)    // 44800
#define NX 160
#define NY 160

// ---------------------------------------------------------------------------
// Kernel 1: combine[b] = rotMtx[b] @ inv(intrins[b])  (f64, 8 tiny matrices)
// ---------------------------------------------------------------------------
__global__ void k_combine(const float* __restrict__ intrins,
                          const float* __restrict__ rot,
                          double* __restrict__ combine) {
    int b = threadIdx.x;
    if (b >= BB) return;
    const float* K = intrins + b * 9;
    const float* R = rot + b * 9;
    double a00 = K[0], a01 = K[1], a02 = K[2];
    double a10 = K[3], a11 = K[4], a12 = K[5];
    double a20 = K[6], a21 = K[7], a22 = K[8];
    double det = a00 * (a11 * a22 - a12 * a21)
               - a01 * (a10 * a22 - a12 * a20)
               + a02 * (a10 * a21 - a11 * a20);
    double inv[9];
    inv[0] =  (a11 * a22 - a12 * a21) / det;
    inv[1] = -(a01 * a22 - a02 * a21) / det;
    inv[2] =  (a01 * a12 - a02 * a11) / det;
    inv[3] = -(a10 * a22 - a12 * a20) / det;
    inv[4] =  (a00 * a22 - a02 * a20) / det;
    inv[5] = -(a00 * a12 - a02 * a10) / det;
    inv[6] =  (a10 * a21 - a11 * a20) / det;
    inv[7] = -(a00 * a21 - a01 * a20) / det;
    inv[8] =  (a00 * a11 - a01 * a10) / det;
    for (int i = 0; i < 3; ++i)
        for (int j = 0; j < 3; ++j) {
            double s = 0.0;
            for (int k = 0; k < 3; ++k) s += (double)R[i * 3 + k] * inv[k * 3 + j];
            combine[b * 9 + i * 3 + j] = s;
        }
}

// ---------------------------------------------------------------------------
// Kernel 2: per-pixel depth argmax + projection + voxelization -> cell id
// Block = 256 threads = 64 pixels x 4 depth-chunks (coalesced 256B/wave reads)
// ---------------------------------------------------------------------------
__global__ __launch_bounds__(256) void k_cells(const float* __restrict__ dlog,
                                               const double* __restrict__ combine,
                                               int* __restrict__ cells) {
    __shared__ float s_best[4][64];
    __shared__ int   s_idx[4][64];
    const int lane = threadIdx.x & 63;
    const int q = threadIdx.x >> 6;      // depth-chunk 0..3 (118 bins each)
    const int pid = blockIdx.x * 64 + lane;   // 700 blocks * 64 = 44800 exact
    const int b = pid / NPIX;
    const int rem = pid - b * NPIX;

    const float* base = dlog + (size_t)b * DD * NPIX + rem;
    float best = -INFINITY;
    int bi = 0;
    const int d0 = q * 118;
    #pragma unroll 4
    for (int k = 0; k < 118; ++k) {
        int dd = d0 + k;
        float v = base[(size_t)dd * NPIX];
        if (v > best) { best = v; bi = dd; }   // strict > : first max wins
    }
    s_best[q][lane] = best;
    s_idx[q][lane] = bi;
    __syncthreads();
    if (q != 0) return;

    // merge chunks in ascending order (preserves first-occurrence tiebreak)
    for (int qq = 1; qq < 4; ++qq) {
        float v = s_best[qq][lane];
        if (v > best) { best = v; bi = s_idx[qq][lane]; }
    }

    // geometry in f64 (tracks the numpy f64 reference's floor decisions)
    const int h = rem / FW;
    const int w = rem - h * FW;
    double d = (double)bi * 0.125 + 1.0;
    double u = (double)w * (1600.0 / 99.0);   // linspace(0,1600,100)
    double v2 = (double)h * (896.0 / 55.0);   // linspace(0,896,56)
    double x0 = u * d, x1 = v2 * d, x2 = d;
    const double* M = combine + b * 9;
    double px = M[0] * x0 + M[1] * x1 + M[2] * x2;
    double py = M[3] * x0 + M[4] * x1 + M[5] * x2;
    double pz = M[6] * x0 + M[7] * x1 + M[8] * x2;

    bool ok = (px > 1.0) && (px < 41.0) &&
              (py > -20.0) && (py < 20.0) &&
              (pz > -10.0) && (pz < 10.0);
    int vx = (int)floor((px - 1.0) / 0.25);
    int vy = (int)floor((py + 20.0) / 0.25);
    int vz = (int)floor((pz + 10.0) / 20.0);
    ok = ok && (vx >= 0) && (vx < NX) && (vy >= 0) && (vy < NY) &&
         (vz >= 0) && (vz < 1);
    cells[pid] = ok ? (b * (NX * NY) + vx * NY + vy) : -1;
}

// ---------------------------------------------------------------------------
// Kernel 3: scatter features of valid pixels into BEV cells (atomicAdd)
// Block = 256 threads = 16 consecutive pixels x 16 channel-lanes.
// Feature reads: 16 consecutive floats per (c) -> coalesced 64B segments.
// Atomics: contiguous 472-float run per cell.
// ---------------------------------------------------------------------------
__global__ __launch_bounds__(256) void k_scatter(const float* __restrict__ feats,
                                                 const int* __restrict__ cells,
                                                 float* __restrict__ out) {
    const int tile = blockIdx.x;            // 2800 tiles of 16 pixels
    const int wi = threadIdx.x & 15;        // pixel within tile
    const int ci0 = threadIdx.x >> 4;       // channel phase 0..15
    const int pid = tile * 16 + wi;         // tiles never straddle a batch (5600%16==0)
    const int cell = cells[pid];

    // whole-tile early out (predicate identical across all 4 waves)
    if (!__any(cell >= 0)) return;
    if (cell < 0) return;

    const int b = pid / NPIX;
    const int rem = pid - b * NPIX;
    const float* fb = feats + (size_t)b * CC * NPIX + rem;
    float* ob = out + (size_t)cell * CC;
    for (int c = ci0; c < CC; c += 16) {
        atomicAdd(ob + c, fb[(size_t)c * NPIX]);
    }
}

// ---------------------------------------------------------------------------
extern "C" void kernel_launch(void* const* d_in, const int* in_sizes, int n_in,
                              void* d_out, int out_size, void* d_ws, size_t ws_size,
                              hipStream_t stream) {
    const float* dlog    = (const float*)d_in[0];
    const float* feats   = (const float*)d_in[1];
    const float* intrins = (const float*)d_in[2];
    const float* rot     = (const float*)d_in[3];
    float* out = (float*)d_out;

    int* cells = (int*)d_ws;
    double* combine = (double*)((char*)d_ws + (((size_t)NPIX_TOT * 4 + 255) & ~(size_t)255));

    // zero the full BEV output (386.6 MB) — harness poisons it before each call
    hipMemsetAsync(d_out, 0, (size_t)out_size * sizeof(float), stream);

    k_combine<<<1, 64, 0, stream>>>(intrins, rot, combine);
    k_cells<<<NPIX_TOT / 64, 256, 0, stream>>>(dlog, combine, cells);
    k_scatter<<<NPIX_TOT / 16, 256, 0, stream>>>(feats, cells, out);
}